// Round 2
// baseline (42303.830 us; speedup 1.0000x reference)
//
#include <hip/hip_runtime.h>

typedef _Float16 f16;
typedef _Float16 f16x4 __attribute__((ext_vector_type(4)));
typedef _Float16 f16x8 __attribute__((ext_vector_type(8)));
typedef float f32x4 __attribute__((ext_vector_type(4)));

#define SEQ 4096
#define NF  2048
#define HID 1024

// ---------------- static device scratch (no d_ws dependence) ----------------
__device__ f16   g_Ahi[SEQ * NF];            // 16 MB
__device__ f16   g_Alo[SEQ * NF];            // 16 MB
__device__ f16   g_Whi[2 * 4096 * NF];       // 33.5 MB
__device__ f16   g_Wlo[2 * 4096 * NF];       // 33.5 MB
__device__ float g_xp [2u * SEQ * 4096u];    // 134 MB
__device__ float g_hist[2u * SEQ * HID];     // 33.5 MB
__device__ float g_hbuf[2 * 2 * HID];        // 16 KB ring (dir, slot, j)
__device__ int   g_flags[2 * 128];           // step-progress flags
__device__ float g_feats[SEQ * 10];

// ---------------- fp32 -> f16 hi/lo split ----------------
// which: 0 -> g_Ahi/g_Alo ; 1 -> g_Whi/g_Wlo dir0 ; 2 -> g_Whi/g_Wlo dir1
__global__ void cvt_split(const float* __restrict__ src, int which, int n4) {
  int i = blockIdx.x * blockDim.x + threadIdx.x;
  int stride = gridDim.x * blockDim.x;
  f16* hi; f16* lo;
  if (which == 0)      { hi = g_Ahi; lo = g_Alo; }
  else if (which == 1) { hi = g_Whi; lo = g_Wlo; }
  else                 { hi = g_Whi + 4096 * NF; lo = g_Wlo + 4096 * NF; }
  const float4* s4 = (const float4*)src;
  f16x4* h4 = (f16x4*)hi;
  f16x4* l4 = (f16x4*)lo;
  for (int idx = i; idx < n4; idx += stride) {
    float4 v = s4[idx];
    f16x4 h, l;
    h.x = (f16)v.x; l.x = (f16)(v.x - (float)h.x);
    h.y = (f16)v.y; l.y = (f16)(v.y - (float)h.y);
    h.z = (f16)v.z; l.z = (f16)(v.z - (float)h.z);
    h.w = (f16)v.w; l.w = (f16)(v.w - (float)h.w);
    h4[idx] = h; l4[idx] = l;
  }
}

// ---------------- xp = A @ W^T + b  (split f16, 3 MFMA products) ----------------
__global__ __launch_bounds__(256, 1) void gemm_xp(
    const float* __restrict__ b_f, const float* __restrict__ b_b)
{
  const int d = blockIdx.z;
  const f16* WhiD = g_Whi + (size_t)d * (4096u * 2048u);
  const f16* WloD = g_Wlo + (size_t)d * (4096u * 2048u);
  const float* bias = d ? b_b : b_f;
  float* out = g_xp + (size_t)d * (4096u * 4096u);

  __shared__ f16 sAh[128 * 40];
  __shared__ f16 sAl[128 * 40];
  __shared__ f16 sWh[128 * 40];
  __shared__ f16 sWl[128 * 40];

  const int tid  = threadIdx.x;
  const int lane = tid & 63;
  const int wv   = tid >> 6;
  const int quad = lane >> 4;
  const int mrow = lane & 15;
  const int m0 = (wv & 1) * 64;
  const int n0 = (wv >> 1) * 64;
  const int bm = blockIdx.y, bn = blockIdx.x;

  f32x4 acc[4][4] = {};

  const int r0  = tid >> 2;   // 0..63
  const int seg = tid & 3;

  for (int kt = 0; kt < 2048; kt += 32) {
#pragma unroll
    for (int r = 0; r < 2; ++r) {
      int row = r * 64 + r0;
      size_t ga = (size_t)(bm * 128 + row) * 2048 + kt + seg * 8;
      size_t gw = (size_t)(bn * 128 + row) * 2048 + kt + seg * 8;
      int lidx = row * 40 + seg * 8;
      *(f16x8*)&sAh[lidx] = *(const f16x8*)&g_Ahi[ga];
      *(f16x8*)&sAl[lidx] = *(const f16x8*)&g_Alo[ga];
      *(f16x8*)&sWh[lidx] = *(const f16x8*)&WhiD[gw];
      *(f16x8*)&sWl[lidx] = *(const f16x8*)&WloD[gw];
    }
    __syncthreads();

    f16x8 ah[4], al[4], wh[4], wl[4];
#pragma unroll
    for (int mi = 0; mi < 4; ++mi) {
      int rowm = (m0 + mi * 16 + mrow) * 40 + quad * 8;
      ah[mi] = *(const f16x8*)&sAh[rowm];
      al[mi] = *(const f16x8*)&sAl[rowm];
    }
#pragma unroll
    for (int ni = 0; ni < 4; ++ni) {
      int rown = (n0 + ni * 16 + mrow) * 40 + quad * 8;
      wh[ni] = *(const f16x8*)&sWh[rown];
      wl[ni] = *(const f16x8*)&sWl[rown];
    }
#pragma unroll
    for (int mi = 0; mi < 4; ++mi)
#pragma unroll
      for (int ni = 0; ni < 4; ++ni) {
        acc[mi][ni] = __builtin_amdgcn_mfma_f32_16x16x32_f16(ah[mi], wh[ni], acc[mi][ni], 0, 0, 0);
        acc[mi][ni] = __builtin_amdgcn_mfma_f32_16x16x32_f16(ah[mi], wl[ni], acc[mi][ni], 0, 0, 0);
        acc[mi][ni] = __builtin_amdgcn_mfma_f32_16x16x32_f16(al[mi], wh[ni], acc[mi][ni], 0, 0, 0);
      }
    __syncthreads();
  }

#pragma unroll
  for (int ni = 0; ni < 4; ++ni) {
    int g = bn * 128 + n0 + ni * 16 + mrow;
    float bv = bias[g];
#pragma unroll
    for (int mi = 0; mi < 4; ++mi) {
#pragma unroll
      for (int r = 0; r < 4; ++r) {
        int t = bm * 128 + m0 + mi * 16 + quad * 4 + r;
        out[(size_t)t * 4096 + g] = acc[mi][ni][r] + bv;
      }
    }
  }
}

// ---------------- per-call sync-state reset ----------------
// Globals persist across graph replays; flags/h0 must be re-initialized
// every call. Kernel boundary on the stream orders this before lstm.
__global__ void init_sync() {
  int i = blockIdx.x * blockDim.x + threadIdx.x;
  if (i < 256) g_flags[i] = 0;                 // "h_0 published"
  if (i < 4096) g_hbuf[i] = 0.f;               // zero both slots, both dirs
}

// ---------------- persistent bidirectional LSTM ----------------
// 256 WGs: dir = bid&1, slice = bid>>1 (128 slices of 8 h-dims each).
// W_hh slice (32 rows x 1024, fp32) lives in VGPRs (128 regs/thread).
// Monotonic flags + double-buffered h ring; agent-scope atomics.
__global__ __launch_bounds__(256, 1) void lstm_persistent(
    const float* __restrict__ Whh_f, const float* __restrict__ Whh_b)
{
  const int bid = blockIdx.x;
  const int dir = bid & 1;
  const int wsl = bid >> 1;     // 0..127
  const int tid = threadIdx.x;
  const int row = tid >> 3;     // 0..31  (gate*8 + jj)
  const int ks  = tid & 7;      // k-section 0..7 (128 k each)
  const int gate = row >> 3;
  const int jj8  = row & 7;

  __shared__ float h_lds[8 * 132];
  __shared__ float gates_lds[32];

  const float* Wd = dir ? Whh_b : Whh_f;
  const int grow = gate * 1024 + wsl * 8 + jj8;
  float4 w4[32];
  {
    const float4* src = (const float4*)(Wd + (size_t)grow * 1024 + ks * 128);
#pragma unroll
    for (int ii = 0; ii < 32; ++ii) w4[ii] = src[ii];
  }

  const float* xpd = g_xp + (size_t)dir * 4096u * 4096u;
  float* hb  = g_hbuf + dir * 2 * 1024;
  int* flg   = g_flags + dir * 128;
  float* histd = g_hist + (size_t)dir * 4096u * 1024u;

  float c = 0.f;

  for (int t = 1; t <= 4096; ++t) {
    const int tau = dir ? (4096 - t) : (t - 1);

    // prefetch this step's xp contribution before the poll
    float xv0 = 0.f, xv1 = 0.f, xv2 = 0.f, xv3 = 0.f;
    if (tid < 8) {
      const float* px = xpd + (size_t)tau * 4096 + wsl * 8 + tid;
      xv0 = px[0]; xv1 = px[1024]; xv2 = px[2048]; xv3 = px[3072];
    }

    // wait for all 128 slices of h_{t-1}
    const int need = t - 1;
    if (tid < 64) {
      bool ok;
      do {
        int a = __hip_atomic_load(&flg[tid],      __ATOMIC_RELAXED, __HIP_MEMORY_SCOPE_AGENT);
        int b = __hip_atomic_load(&flg[64 + tid], __ATOMIC_RELAXED, __HIP_MEMORY_SCOPE_AGENT);
        ok = (a >= need) && (b >= need);
      } while (!__all(ok));
      __builtin_amdgcn_fence(__ATOMIC_ACQUIRE, "agent");
    }
    __syncthreads();

    // gather h_{t-1} (full 1024) into LDS
    {
      const float* hsrc = hb + ((t - 1) & 1) * 1024;
      int k0 = tid * 4;
      float a  = __hip_atomic_load(&hsrc[k0 + 0], __ATOMIC_RELAXED, __HIP_MEMORY_SCOPE_AGENT);
      float b  = __hip_atomic_load(&hsrc[k0 + 1], __ATOMIC_RELAXED, __HIP_MEMORY_SCOPE_AGENT);
      float c2 = __hip_atomic_load(&hsrc[k0 + 2], __ATOMIC_RELAXED, __HIP_MEMORY_SCOPE_AGENT);
      float d2 = __hip_atomic_load(&hsrc[k0 + 3], __ATOMIC_RELAXED, __HIP_MEMORY_SCOPE_AGENT);
      *(float4*)&h_lds[(k0 >> 7) * 132 + (k0 & 127)] = make_float4(a, b, c2, d2);
    }
    __syncthreads();

    // GEMV slice: 32 rows x 1024, 8 lanes per row
    float acc = 0.f;
    const float4* h4 = (const float4*)&h_lds[ks * 132];
#pragma unroll
    for (int ii = 0; ii < 32; ++ii) {
      float4 hv = h4[ii];
      acc += w4[ii].x * hv.x;
      acc += w4[ii].y * hv.y;
      acc += w4[ii].z * hv.z;
      acc += w4[ii].w * hv.w;
    }
    acc += __shfl_xor(acc, 1);
    acc += __shfl_xor(acc, 2);
    acc += __shfl_xor(acc, 4);
    if (ks == 0) gates_lds[row] = acc;
    __syncthreads();

    // elementwise cell update (8 h-dims per WG)
    if (tid < 8) {
      float gi = gates_lds[tid]      + xv0;
      float gf = gates_lds[8 + tid]  + xv1;
      float gg = gates_lds[16 + tid] + xv2;
      float go = gates_lds[24 + tid] + xv3;
      float si = 1.f / (1.f + __expf(-gi));
      float sf = 1.f / (1.f + __expf(-gf));
      float so = 1.f / (1.f + __expf(-go));
      float tg = 1.f - 2.f / (1.f + __expf(2.f * gg));
      c = sf * c + si * tg;
      float th = 1.f - 2.f / (1.f + __expf(2.f * c));
      float h  = so * th;
      __hip_atomic_store(&hb[(t & 1) * 1024 + wsl * 8 + tid], h,
                         __ATOMIC_RELAXED, __HIP_MEMORY_SCOPE_AGENT);
      histd[(size_t)tau * 1024 + wsl * 8 + tid] = h;
    }
    __syncthreads();   // drains h stores before publish
    if (tid == 0) {
      __builtin_amdgcn_fence(__ATOMIC_RELEASE, "agent");
      __hip_atomic_store(&flg[wsl], t, __ATOMIC_RELAXED, __HIP_MEMORY_SCOPE_AGENT);
    }
  }
}

// ---------------- feats = concat(h_f,h_b) @ W_lin^T + b_lin ----------------
__global__ __launch_bounds__(256, 1) void feats_kernel(
    const float* __restrict__ W_lin, const float* __restrict__ b_lin)
{
  const int tid = threadIdx.x;
  const int wv = tid >> 6, l = tid & 63;
  const int t0 = blockIdx.x * 16 + wv * 4;
  for (int it = 0; it < 4; ++it) {
    const int t = t0 + it;
    float hf[16], hbv[16];
#pragma unroll
    for (int i = 0; i < 16; ++i) hf[i]  = g_hist[(size_t)t * 1024 + l + 64 * i];
#pragma unroll
    for (int i = 0; i < 16; ++i) hbv[i] = g_hist[(size_t)(4096 + t) * 1024 + l + 64 * i];
#pragma unroll
    for (int tag = 0; tag < 10; ++tag) {
      float a = 0.f;
#pragma unroll
      for (int i = 0; i < 16; ++i) {
        a += W_lin[tag * 2048 + l + 64 * i] * hf[i];
        a += W_lin[tag * 2048 + 1024 + l + 64 * i] * hbv[i];
      }
      a += __shfl_xor(a, 32); a += __shfl_xor(a, 16); a += __shfl_xor(a, 8);
      a += __shfl_xor(a, 4);  a += __shfl_xor(a, 2);  a += __shfl_xor(a, 1);
      if (l == 0) g_feats[t * 10 + tag] = a + b_lin[tag];
    }
  }
}

// ---------------- Viterbi forward + backtrack ----------------
__global__ __launch_bounds__(64, 1) void viterbi_kernel(
    const float* __restrict__ trans, float* __restrict__ out)
{
  __shared__ unsigned char bps[4096 * 10];  // 40 KB
  const int to = threadIdx.x;
  float tr[10];
#pragma unroll
  for (int f = 0; f < 10; ++f) tr[f] = (to < 10) ? trans[to * 10 + f] : 0.f;
  float fv = (to == 8) ? 0.f : -10000.f;   // START_TAG = 8

  float fbuf[8];
#pragma unroll
  for (int i = 0; i < 8; ++i) fbuf[i] = (to < 10) ? g_feats[i * 10 + to] : 0.f;

  for (int t = 0; t < 4096; t += 8) {
#pragma unroll
    for (int u = 0; u < 8; ++u) {
      const int tt = t + u;
      float m = -3.4e38f; int am = 0;
#pragma unroll
      for (int f = 0; f < 10; ++f) {
        float v = __shfl(fv, f) + tr[f];
        if (v > m) { m = v; am = f; }   // strict > keeps FIRST argmax
      }
      float ft = fbuf[u];
      if (tt + 8 < 4096 && to < 10) fbuf[u] = g_feats[(tt + 8) * 10 + to];
      fv = m + ft;
      if (to < 10) bps[tt * 10 + to] = (unsigned char)am;
    }
  }
  __syncthreads();

  float term = fv + ((to < 10) ? trans[90 + to] : -3.4e38f);  // STOP_TAG row
  float best = -3.4e38f; int bl = 0;
#pragma unroll
  for (int f = 0; f < 10; ++f) {
    float v = __shfl(term, f);
    if (v > best) { best = v; bl = f; }
  }
  if (to == 0) {
    out[0] = best;
    int tag = bl;
    for (int t = 4095; t >= 0; --t) {
      out[1 + t] = (float)tag;
      tag = bps[t * 10 + tag];
    }
  }
}

// ---------------- launch ----------------
extern "C" void kernel_launch(void* const* d_in, const int* in_sizes, int n_in,
                              void* d_out, int out_size, void* d_ws, size_t ws_size,
                              hipStream_t stream)
{
  (void)in_sizes; (void)n_in; (void)out_size; (void)d_ws; (void)ws_size;
  const float* sentence = (const float*)d_in[0];
  const float* W_hh_f   = (const float*)d_in[2];
  const float* b_f      = (const float*)d_in[3];
  const float* W_hh_b   = (const float*)d_in[5];
  const float* b_b      = (const float*)d_in[6];
  const float* W_lin    = (const float*)d_in[7];
  const float* b_lin    = (const float*)d_in[8];
  const float* trans    = (const float*)d_in[9];

  cvt_split<<<1024, 256, 0, stream>>>((const float*)d_in[0], 0, 2097152);
  cvt_split<<<1024, 256, 0, stream>>>((const float*)d_in[1], 1, 2097152);
  cvt_split<<<1024, 256, 0, stream>>>((const float*)d_in[4], 2, 2097152);
  (void)sentence;

  gemm_xp<<<dim3(32, 32, 2), 256, 0, stream>>>(b_f, b_b);

  init_sync<<<16, 256, 0, stream>>>();

  lstm_persistent<<<256, 256, 0, stream>>>(W_hh_f, W_hh_b);

  feats_kernel<<<256, 256, 0, stream>>>(W_lin, b_lin);

  viterbi_kernel<<<1, 64, 0, stream>>>(trans, (float*)d_out);
}

// Round 3
// 13778.760 us; speedup vs baseline: 3.0702x; 3.0702x over previous
//
#include <hip/hip_runtime.h>

typedef _Float16 f16;
typedef _Float16 f16x4 __attribute__((ext_vector_type(4)));
typedef _Float16 f16x8 __attribute__((ext_vector_type(8)));
typedef float f32x4 __attribute__((ext_vector_type(4)));

#define SEQ 4096
#define NF  2048
#define HID 1024

// ---------------- static device scratch ----------------
__device__ f16   g_Ahi[SEQ * NF];
__device__ f16   g_Alo[SEQ * NF];
__device__ f16   g_Whi[2 * 4096 * NF];
__device__ f16   g_Wlo[2 * 4096 * NF];
__device__ float g_xp [2u * SEQ * 4096u];          // [dir][t][4096]
__device__ float g_hist[2u * SEQ * HID];           // [dir][t][1024]
__device__ unsigned long long g_ring[2][2][1024];  // [dir][slot][j] = tag<<32 | h_bits
__device__ float g_feats[SEQ * 10];

// ---------------- fp32 -> f16 hi/lo split ----------------
__global__ void cvt_split(const float* __restrict__ src, int which, int n4) {
  int i = blockIdx.x * blockDim.x + threadIdx.x;
  int stride = gridDim.x * blockDim.x;
  f16* hi; f16* lo;
  if (which == 0)      { hi = g_Ahi; lo = g_Alo; }
  else if (which == 1) { hi = g_Whi; lo = g_Wlo; }
  else                 { hi = g_Whi + 4096 * NF; lo = g_Wlo + 4096 * NF; }
  const float4* s4 = (const float4*)src;
  f16x4* h4 = (f16x4*)hi;
  f16x4* l4 = (f16x4*)lo;
  for (int idx = i; idx < n4; idx += stride) {
    float4 v = s4[idx];
    f16x4 h, l;
    h.x = (f16)v.x; l.x = (f16)(v.x - (float)h.x);
    h.y = (f16)v.y; l.y = (f16)(v.y - (float)h.y);
    h.z = (f16)v.z; l.z = (f16)(v.z - (float)h.z);
    h.w = (f16)v.w; l.w = (f16)(v.w - (float)h.w);
    h4[idx] = h; l4[idx] = l;
  }
}

// ---------------- xp = A @ W^T + b  (split f16, 3 MFMA products) ----------------
__global__ __launch_bounds__(256, 1) void gemm_xp(
    const float* __restrict__ b_f, const float* __restrict__ b_b)
{
  const int d = blockIdx.z;
  const f16* WhiD = g_Whi + (size_t)d * (4096u * 2048u);
  const f16* WloD = g_Wlo + (size_t)d * (4096u * 2048u);
  const float* bias = d ? b_b : b_f;
  float* out = g_xp + (size_t)d * (4096u * 4096u);

  __shared__ f16 sAh[128 * 40];
  __shared__ f16 sAl[128 * 40];
  __shared__ f16 sWh[128 * 40];
  __shared__ f16 sWl[128 * 40];

  const int tid  = threadIdx.x;
  const int lane = tid & 63;
  const int wv   = tid >> 6;
  const int quad = lane >> 4;
  const int mrow = lane & 15;
  const int m0 = (wv & 1) * 64;
  const int n0 = (wv >> 1) * 64;
  const int bm = blockIdx.y, bn = blockIdx.x;

  f32x4 acc[4][4] = {};

  const int r0  = tid >> 2;
  const int seg = tid & 3;

  for (int kt = 0; kt < 2048; kt += 32) {
#pragma unroll
    for (int r = 0; r < 2; ++r) {
      int row = r * 64 + r0;
      size_t ga = (size_t)(bm * 128 + row) * 2048 + kt + seg * 8;
      size_t gw = (size_t)(bn * 128 + row) * 2048 + kt + seg * 8;
      int lidx = row * 40 + seg * 8;
      *(f16x8*)&sAh[lidx] = *(const f16x8*)&g_Ahi[ga];
      *(f16x8*)&sAl[lidx] = *(const f16x8*)&g_Alo[ga];
      *(f16x8*)&sWh[lidx] = *(const f16x8*)&WhiD[gw];
      *(f16x8*)&sWl[lidx] = *(const f16x8*)&WloD[gw];
    }
    __syncthreads();

    f16x8 ah[4], al[4], wh[4], wl[4];
#pragma unroll
    for (int mi = 0; mi < 4; ++mi) {
      int rowm = (m0 + mi * 16 + mrow) * 40 + quad * 8;
      ah[mi] = *(const f16x8*)&sAh[rowm];
      al[mi] = *(const f16x8*)&sAl[rowm];
    }
#pragma unroll
    for (int ni = 0; ni < 4; ++ni) {
      int rown = (n0 + ni * 16 + mrow) * 40 + quad * 8;
      wh[ni] = *(const f16x8*)&sWh[rown];
      wl[ni] = *(const f16x8*)&sWl[rown];
    }
#pragma unroll
    for (int mi = 0; mi < 4; ++mi)
#pragma unroll
      for (int ni = 0; ni < 4; ++ni) {
        acc[mi][ni] = __builtin_amdgcn_mfma_f32_16x16x32_f16(ah[mi], wh[ni], acc[mi][ni], 0, 0, 0);
        acc[mi][ni] = __builtin_amdgcn_mfma_f32_16x16x32_f16(ah[mi], wl[ni], acc[mi][ni], 0, 0, 0);
        acc[mi][ni] = __builtin_amdgcn_mfma_f32_16x16x32_f16(al[mi], wh[ni], acc[mi][ni], 0, 0, 0);
      }
    __syncthreads();
  }

#pragma unroll
  for (int ni = 0; ni < 4; ++ni) {
    int g = bn * 128 + n0 + ni * 16 + mrow;
    float bv = bias[g];
#pragma unroll
    for (int mi = 0; mi < 4; ++mi) {
#pragma unroll
      for (int r = 0; r < 4; ++r) {
        int t = bm * 128 + m0 + mi * 16 + quad * 4 + r;
        out[(size_t)t * 4096 + g] = acc[mi][ni][r] + bv;
      }
    }
  }
}

// ---------------- per-call ring reset (graph-replay safe) ----------------
__global__ void init_sync() {
  int i = blockIdx.x * blockDim.x + threadIdx.x;
  // 2 dirs x 2 slots x 1024 = 4096 u64; tag 0, h = 0.0f
  ((unsigned long long*)g_ring)[i] = 0ull;
}

// ---------------- persistent bidirectional LSTM ----------------
// 256 WGs x 512 threads. dir = bid&1, wsl = bid>>1 (8 h-dims per WG).
// Each WG computes 32 rows (4 gates x 8 j) of the 4096x1024 GEMV.
// Wave w owns rows 4w..4w+3; lane i owns k-chunks {4i+256j : j=0..3}
// -> 16 float4 of W_hh per thread, held in VGPRs.
// Sync: h element published as one atomic u64 (tag<<32 | bits) into a
// 2-slot ring -> tag+data arrive atomically, NO fences, no flag hop.
__global__ __launch_bounds__(512, 1) void lstm_persistent(
    const float* __restrict__ Whh_f, const float* __restrict__ Whh_b)
{
  const int bid = blockIdx.x;
  const int dir = bid & 1;
  const int wsl = bid >> 1;        // 0..127
  const int tid = threadIdx.x;
  const int w   = tid >> 6;        // wave 0..7
  const int i   = tid & 63;        // lane

  __shared__ float h_lds[1024];
  __shared__ float gates_lds[32];

  const float* Wd = dir ? Whh_b : Whh_f;

  // weights: rows 4w..4w+3, cols {4i+256j}
  float4 w4[4][4];
#pragma unroll
  for (int r = 0; r < 4; ++r) {
    int rl = 4 * w + r;                               // row_local 0..31
    int grow = (rl >> 3) * 1024 + wsl * 8 + (rl & 7); // global row in W_hh
#pragma unroll
    for (int j = 0; j < 4; ++j)
      w4[r][j] = *(const float4*)&Wd[(size_t)grow * 1024 + 4 * i + 256 * j];
  }

  const float* xpd = g_xp + (size_t)dir * 4096u * 4096u;
  float* histd = g_hist + (size_t)dir * 4096u * 1024u;

  float c = 0.f;
  const int e0 = 2 * tid, e1 = 2 * tid + 1;

  for (int t = 1; t <= 4096; ++t) {
    const int tau = dir ? (4096 - t) : (t - 1);

    // prefetch xp contribution (consumed in the update stage)
    float xv0 = 0.f, xv1 = 0.f, xv2 = 0.f, xv3 = 0.f;
    if (tid < 8) {
      const float* px = xpd + (size_t)tau * 4096 + wsl * 8 + tid;
      xv0 = px[0]; xv1 = px[1024]; xv2 = px[2048]; xv3 = px[3072];
    }

    // poll ring for h_{t-1}: each thread owns 2 elements
    {
      const unsigned need = (unsigned)(t - 1);
      unsigned long long* rs = &g_ring[dir][(t - 1) & 1][0];
      unsigned long long v0 = __hip_atomic_load(&rs[e0], __ATOMIC_RELAXED, __HIP_MEMORY_SCOPE_AGENT);
      unsigned long long v1 = __hip_atomic_load(&rs[e1], __ATOMIC_RELAXED, __HIP_MEMORY_SCOPE_AGENT);
      while ((unsigned)(v0 >> 32) != need || (unsigned)(v1 >> 32) != need) {
        __builtin_amdgcn_s_sleep(1);
        if ((unsigned)(v0 >> 32) != need)
          v0 = __hip_atomic_load(&rs[e0], __ATOMIC_RELAXED, __HIP_MEMORY_SCOPE_AGENT);
        if ((unsigned)(v1 >> 32) != need)
          v1 = __hip_atomic_load(&rs[e1], __ATOMIC_RELAXED, __HIP_MEMORY_SCOPE_AGENT);
      }
      float2 hv; hv.x = __uint_as_float((unsigned)v0); hv.y = __uint_as_float((unsigned)v1);
      *(float2*)&h_lds[e0] = hv;
    }
    __syncthreads();

    // GEMV: 4 rows x 16 k per thread
    float a0 = 0.f, a1 = 0.f, a2 = 0.f, a3 = 0.f;
#pragma unroll
    for (int j = 0; j < 4; ++j) {
      float4 hv = *(const float4*)&h_lds[4 * i + 256 * j];
      a0 += w4[0][j].x * hv.x + w4[0][j].y * hv.y + w4[0][j].z * hv.z + w4[0][j].w * hv.w;
      a1 += w4[1][j].x * hv.x + w4[1][j].y * hv.y + w4[1][j].z * hv.z + w4[1][j].w * hv.w;
      a2 += w4[2][j].x * hv.x + w4[2][j].y * hv.y + w4[2][j].z * hv.z + w4[2][j].w * hv.w;
      a3 += w4[3][j].x * hv.x + w4[3][j].y * hv.y + w4[3][j].z * hv.z + w4[3][j].w * hv.w;
    }
#pragma unroll
    for (int s = 1; s < 64; s <<= 1) {
      a0 += __shfl_xor(a0, s);
      a1 += __shfl_xor(a1, s);
      a2 += __shfl_xor(a2, s);
      a3 += __shfl_xor(a3, s);
    }
    if (i == 0) {
      gates_lds[4 * w + 0] = a0;
      gates_lds[4 * w + 1] = a1;
      gates_lds[4 * w + 2] = a2;
      gates_lds[4 * w + 3] = a3;
    }
    __syncthreads();

    // cell update: 8 h-dims, one per thread 0..7
    if (tid < 8) {
      float gi = gates_lds[tid]      + xv0;
      float gf = gates_lds[8 + tid]  + xv1;
      float gg = gates_lds[16 + tid] + xv2;
      float go = gates_lds[24 + tid] + xv3;
      float si = 1.f / (1.f + __expf(-gi));
      float sf = 1.f / (1.f + __expf(-gf));
      float so = 1.f / (1.f + __expf(-go));
      float tg = 1.f - 2.f / (1.f + __expf(2.f * gg));
      c = sf * c + si * tg;
      float th = 1.f - 2.f / (1.f + __expf(2.f * c));
      float h  = so * th;
      histd[(size_t)tau * 1024 + wsl * 8 + tid] = h;
      unsigned long long pk = ((unsigned long long)(unsigned)t << 32)
                            | (unsigned long long)__float_as_uint(h);
      __hip_atomic_store(&g_ring[dir][t & 1][wsl * 8 + tid], pk,
                         __ATOMIC_RELAXED, __HIP_MEMORY_SCOPE_AGENT);
    }
    // no trailing barrier needed: h_lds rewrites in t+1 are fenced by the
    // post-poll barrier; gates_lds rewrites by the post-GEMV barrier.
  }
}

// ---------------- feats = concat(h_f,h_b) @ W_lin^T + b_lin ----------------
__global__ __launch_bounds__(256, 1) void feats_kernel(
    const float* __restrict__ W_lin, const float* __restrict__ b_lin)
{
  const int tid = threadIdx.x;
  const int wv = tid >> 6, l = tid & 63;
  const int t0 = blockIdx.x * 16 + wv * 4;
  for (int it = 0; it < 4; ++it) {
    const int t = t0 + it;
    float hf[16], hbv[16];
#pragma unroll
    for (int i = 0; i < 16; ++i) hf[i]  = g_hist[(size_t)t * 1024 + l + 64 * i];
#pragma unroll
    for (int i = 0; i < 16; ++i) hbv[i] = g_hist[(size_t)(4096 + t) * 1024 + l + 64 * i];
#pragma unroll
    for (int tag = 0; tag < 10; ++tag) {
      float a = 0.f;
#pragma unroll
      for (int i = 0; i < 16; ++i) {
        a += W_lin[tag * 2048 + l + 64 * i] * hf[i];
        a += W_lin[tag * 2048 + 1024 + l + 64 * i] * hbv[i];
      }
      a += __shfl_xor(a, 32); a += __shfl_xor(a, 16); a += __shfl_xor(a, 8);
      a += __shfl_xor(a, 4);  a += __shfl_xor(a, 2);  a += __shfl_xor(a, 1);
      if (l == 0) g_feats[t * 10 + tag] = a + b_lin[tag];
    }
  }
}

// ---------------- Viterbi forward + backtrack ----------------
__global__ __launch_bounds__(64, 1) void viterbi_kernel(
    const float* __restrict__ trans, float* __restrict__ out)
{
  __shared__ unsigned char bps[4096 * 10];
  const int to = threadIdx.x;
  float tr[10];
#pragma unroll
  for (int f = 0; f < 10; ++f) tr[f] = (to < 10) ? trans[to * 10 + f] : 0.f;
  float fv = (to == 8) ? 0.f : -10000.f;   // START_TAG = 8

  float fbuf[8];
#pragma unroll
  for (int i = 0; i < 8; ++i) fbuf[i] = (to < 10) ? g_feats[i * 10 + to] : 0.f;

  for (int t = 0; t < 4096; t += 8) {
#pragma unroll
    for (int u = 0; u < 8; ++u) {
      const int tt = t + u;
      float m = -3.4e38f; int am = 0;
#pragma unroll
      for (int f = 0; f < 10; ++f) {
        float v = __shfl(fv, f) + tr[f];
        if (v > m) { m = v; am = f; }
      }
      float ft = fbuf[u];
      if (tt + 8 < 4096 && to < 10) fbuf[u] = g_feats[(tt + 8) * 10 + to];
      fv = m + ft;
      if (to < 10) bps[tt * 10 + to] = (unsigned char)am;
    }
  }
  __syncthreads();

  float term = fv + ((to < 10) ? trans[90 + to] : -3.4e38f);  // STOP_TAG row
  float best = -3.4e38f; int bl = 0;
#pragma unroll
  for (int f = 0; f < 10; ++f) {
    float v = __shfl(term, f);
    if (v > best) { best = v; bl = f; }
  }
  if (to == 0) {
    out[0] = best;
    int tag = bl;
    for (int t = 4095; t >= 0; --t) {
      out[1 + t] = (float)tag;
      tag = bps[t * 10 + tag];
    }
  }
}

// ---------------- launch ----------------
extern "C" void kernel_launch(void* const* d_in, const int* in_sizes, int n_in,
                              void* d_out, int out_size, void* d_ws, size_t ws_size,
                              hipStream_t stream)
{
  (void)in_sizes; (void)n_in; (void)out_size; (void)d_ws; (void)ws_size;
  const float* W_hh_f   = (const float*)d_in[2];
  const float* b_f      = (const float*)d_in[3];
  const float* W_hh_b   = (const float*)d_in[5];
  const float* b_b      = (const float*)d_in[6];
  const float* W_lin    = (const float*)d_in[7];
  const float* b_lin    = (const float*)d_in[8];
  const float* trans    = (const float*)d_in[9];

  cvt_split<<<1024, 256, 0, stream>>>((const float*)d_in[0], 0, 2097152);
  cvt_split<<<1024, 256, 0, stream>>>((const float*)d_in[1], 1, 2097152);
  cvt_split<<<1024, 256, 0, stream>>>((const float*)d_in[4], 2, 2097152);

  gemm_xp<<<dim3(32, 32, 2), 256, 0, stream>>>(b_f, b_b);

  init_sync<<<16, 256, 0, stream>>>();

  lstm_persistent<<<256, 512, 0, stream>>>(W_hh_f, W_hh_b);

  feats_kernel<<<256, 256, 0, stream>>>(W_lin, b_lin);

  viterbi_kernel<<<1, 64, 0, stream>>>(trans, (float*)d_out);
}

// Round 4
// 13264.059 us; speedup vs baseline: 3.1894x; 1.0388x over previous
//
#include <hip/hip_runtime.h>

typedef _Float16 f16;
typedef _Float16 f16x4 __attribute__((ext_vector_type(4)));
typedef _Float16 f16x8 __attribute__((ext_vector_type(8)));
typedef float f32x4 __attribute__((ext_vector_type(4)));

#define SEQ 4096
#define NF  2048
#define HID 1024

// ---------------- static device scratch ----------------
__device__ f16   g_Ahi[SEQ * NF];
__device__ f16   g_Alo[SEQ * NF];
__device__ f16   g_Whi[2 * 4096 * NF];
__device__ f16   g_Wlo[2 * 4096 * NF];
__device__ float g_xp [2u * SEQ * 4096u];          // [dir][t][4096]
__device__ float g_hist[2u * SEQ * HID];           // [dir][t][1024]
__device__ unsigned long long g_ring[2][2][1024];  // [dir][slot][j] = tag<<32 | h_bits
__device__ float g_feats[SEQ * 10];

// ---------------- fp32 -> f16 hi/lo split ----------------
__global__ void cvt_split(const float* __restrict__ src, int which, int n4) {
  int i = blockIdx.x * blockDim.x + threadIdx.x;
  int stride = gridDim.x * blockDim.x;
  f16* hi; f16* lo;
  if (which == 0)      { hi = g_Ahi; lo = g_Alo; }
  else if (which == 1) { hi = g_Whi; lo = g_Wlo; }
  else                 { hi = g_Whi + 4096 * NF; lo = g_Wlo + 4096 * NF; }
  const float4* s4 = (const float4*)src;
  f16x4* h4 = (f16x4*)hi;
  f16x4* l4 = (f16x4*)lo;
  for (int idx = i; idx < n4; idx += stride) {
    float4 v = s4[idx];
    f16x4 h, l;
    h.x = (f16)v.x; l.x = (f16)(v.x - (float)h.x);
    h.y = (f16)v.y; l.y = (f16)(v.y - (float)h.y);
    h.z = (f16)v.z; l.z = (f16)(v.z - (float)h.z);
    h.w = (f16)v.w; l.w = (f16)(v.w - (float)h.w);
    h4[idx] = h; l4[idx] = l;
  }
}

// ---------------- xp = A @ W^T + b  (split f16, 3 MFMA products) ----------------
__global__ __launch_bounds__(256, 1) void gemm_xp(
    const float* __restrict__ b_f, const float* __restrict__ b_b)
{
  const int d = blockIdx.z;
  const f16* WhiD = g_Whi + (size_t)d * (4096u * 2048u);
  const f16* WloD = g_Wlo + (size_t)d * (4096u * 2048u);
  const float* bias = d ? b_b : b_f;
  float* out = g_xp + (size_t)d * (4096u * 4096u);

  __shared__ f16 sAh[128 * 40];
  __shared__ f16 sAl[128 * 40];
  __shared__ f16 sWh[128 * 40];
  __shared__ f16 sWl[128 * 40];

  const int tid  = threadIdx.x;
  const int lane = tid & 63;
  const int wv   = tid >> 6;
  const int quad = lane >> 4;
  const int mrow = lane & 15;
  const int m0 = (wv & 1) * 64;
  const int n0 = (wv >> 1) * 64;
  const int bm = blockIdx.y, bn = blockIdx.x;

  f32x4 acc[4][4] = {};

  const int r0  = tid >> 2;
  const int seg = tid & 3;

  for (int kt = 0; kt < 2048; kt += 32) {
#pragma unroll
    for (int r = 0; r < 2; ++r) {
      int row = r * 64 + r0;
      size_t ga = (size_t)(bm * 128 + row) * 2048 + kt + seg * 8;
      size_t gw = (size_t)(bn * 128 + row) * 2048 + kt + seg * 8;
      int lidx = row * 40 + seg * 8;
      *(f16x8*)&sAh[lidx] = *(const f16x8*)&g_Ahi[ga];
      *(f16x8*)&sAl[lidx] = *(const f16x8*)&g_Alo[ga];
      *(f16x8*)&sWh[lidx] = *(const f16x8*)&WhiD[gw];
      *(f16x8*)&sWl[lidx] = *(const f16x8*)&WloD[gw];
    }
    __syncthreads();

    f16x8 ah[4], al[4], wh[4], wl[4];
#pragma unroll
    for (int mi = 0; mi < 4; ++mi) {
      int rowm = (m0 + mi * 16 + mrow) * 40 + quad * 8;
      ah[mi] = *(const f16x8*)&sAh[rowm];
      al[mi] = *(const f16x8*)&sAl[rowm];
    }
#pragma unroll
    for (int ni = 0; ni < 4; ++ni) {
      int rown = (n0 + ni * 16 + mrow) * 40 + quad * 8;
      wh[ni] = *(const f16x8*)&sWh[rown];
      wl[ni] = *(const f16x8*)&sWl[rown];
    }
#pragma unroll
    for (int mi = 0; mi < 4; ++mi)
#pragma unroll
      for (int ni = 0; ni < 4; ++ni) {
        acc[mi][ni] = __builtin_amdgcn_mfma_f32_16x16x32_f16(ah[mi], wh[ni], acc[mi][ni], 0, 0, 0);
        acc[mi][ni] = __builtin_amdgcn_mfma_f32_16x16x32_f16(ah[mi], wl[ni], acc[mi][ni], 0, 0, 0);
        acc[mi][ni] = __builtin_amdgcn_mfma_f32_16x16x32_f16(al[mi], wh[ni], acc[mi][ni], 0, 0, 0);
      }
    __syncthreads();
  }

#pragma unroll
  for (int ni = 0; ni < 4; ++ni) {
    int g = bn * 128 + n0 + ni * 16 + mrow;
    float bv = bias[g];
#pragma unroll
    for (int mi = 0; mi < 4; ++mi) {
#pragma unroll
      for (int r = 0; r < 4; ++r) {
        int t = bm * 128 + m0 + mi * 16 + quad * 4 + r;
        out[(size_t)t * 4096 + g] = acc[mi][ni][r] + bv;
      }
    }
  }
}

// ---------------- per-call ring reset (graph-replay safe) ----------------
__global__ void init_sync() {
  int i = blockIdx.x * blockDim.x + threadIdx.x;
  ((unsigned long long*)g_ring)[i] = 0ull;   // tag 0, h = 0.0f
}

// ---------------- persistent bidirectional LSTM ----------------
// 256 WGs x 512 threads. dir = bid&1, wsl = bid>>1 (8 h-dims per WG).
// Row r = tid>>4 (32 rows = 4 gates x 8 j), 16 lanes per row.
// Thread covers k in {4*l16 + 64*j : j=0..15} -> 16 float4 of W_hh,
// PINNED into VGPRs via opaque asm (the compiler kept sinking/spilling
// the loop-invariant loads into the 4096-step loop: VGPR_Count was 56).
// Sync: h element published as one atomic u64 (tag<<32 | bits) into a
// 2-slot ring -> tag+data arrive atomically, NO fences.
__global__ __launch_bounds__(512, 2) void lstm_persistent(
    const float* __restrict__ Whh_f, const float* __restrict__ Whh_b)
{
  const int bid = blockIdx.x;
  const int dir = bid & 1;
  const int wsl = bid >> 1;        // 0..127
  const int tid = threadIdx.x;
  const int r   = tid >> 4;        // local row 0..31 (gate = r>>3, jj = r&7)
  const int l16 = tid & 15;

  __shared__ float h_lds[1024];
  __shared__ float gates_lds[32];

  const float* Wd = dir ? Whh_b : Whh_f;

  // one-time weight load: row grow, cols 4*l16 + 64*j
  const int grow = (r >> 3) * 1024 + wsl * 8 + (r & 7);
  float4 w4[16];
#pragma unroll
  for (int j = 0; j < 16; ++j)
    w4[j] = *(const float4*)&Wd[(size_t)grow * 1024 + 4 * l16 + 64 * j];
  // pin as opaque register values — cannot be rematerialized from memory
#pragma unroll
  for (int j = 0; j < 16; ++j)
    asm volatile("" : "+v"(w4[j].x), "+v"(w4[j].y), "+v"(w4[j].z), "+v"(w4[j].w));

  const float* xpd = g_xp + (size_t)dir * 4096u * 4096u;
  float* histd = g_hist + (size_t)dir * 4096u * 1024u;

  float c = 0.f;
  const int e0 = 2 * tid, e1 = 2 * tid + 1;

  for (int t = 1; t <= 4096; ++t) {
    const int tau = dir ? (4096 - t) : (t - 1);

    // prefetch xp contribution (consumed in the update stage)
    float xv0 = 0.f, xv1 = 0.f, xv2 = 0.f, xv3 = 0.f;
    if (tid < 8) {
      const float* px = xpd + (size_t)tau * 4096 + wsl * 8 + tid;
      xv0 = px[0]; xv1 = px[1024]; xv2 = px[2048]; xv3 = px[3072];
    }

    // poll ring for h_{t-1}: each thread owns 2 elements
    {
      const unsigned need = (unsigned)(t - 1);
      unsigned long long* rs = &g_ring[dir][(t - 1) & 1][0];
      unsigned long long v0 = __hip_atomic_load(&rs[e0], __ATOMIC_RELAXED, __HIP_MEMORY_SCOPE_AGENT);
      unsigned long long v1 = __hip_atomic_load(&rs[e1], __ATOMIC_RELAXED, __HIP_MEMORY_SCOPE_AGENT);
      while ((unsigned)(v0 >> 32) != need || (unsigned)(v1 >> 32) != need) {
        __builtin_amdgcn_s_sleep(1);
        if ((unsigned)(v0 >> 32) != need)
          v0 = __hip_atomic_load(&rs[e0], __ATOMIC_RELAXED, __HIP_MEMORY_SCOPE_AGENT);
        if ((unsigned)(v1 >> 32) != need)
          v1 = __hip_atomic_load(&rs[e1], __ATOMIC_RELAXED, __HIP_MEMORY_SCOPE_AGENT);
      }
      float2 hv; hv.x = __uint_as_float((unsigned)v0); hv.y = __uint_as_float((unsigned)v1);
      *(float2*)&h_lds[e0] = hv;
    }
    __syncthreads();

    // GEMV: 1 row x 64 k per thread, 4-way ILP partials
    float p0 = 0.f, p1 = 0.f, p2 = 0.f, p3 = 0.f;
#pragma unroll
    for (int j = 0; j < 16; j += 4) {
      float4 h0 = *(const float4*)&h_lds[4 * l16 + 64 * (j + 0)];
      float4 h1 = *(const float4*)&h_lds[4 * l16 + 64 * (j + 1)];
      float4 h2 = *(const float4*)&h_lds[4 * l16 + 64 * (j + 2)];
      float4 h3 = *(const float4*)&h_lds[4 * l16 + 64 * (j + 3)];
      p0 += w4[j+0].x*h0.x + w4[j+0].y*h0.y + w4[j+0].z*h0.z + w4[j+0].w*h0.w;
      p1 += w4[j+1].x*h1.x + w4[j+1].y*h1.y + w4[j+1].z*h1.z + w4[j+1].w*h1.w;
      p2 += w4[j+2].x*h2.x + w4[j+2].y*h2.y + w4[j+2].z*h2.z + w4[j+2].w*h2.w;
      p3 += w4[j+3].x*h3.x + w4[j+3].y*h3.y + w4[j+3].z*h3.z + w4[j+3].w*h3.w;
    }
    float acc = (p0 + p1) + (p2 + p3);
    acc += __shfl_xor(acc, 1);
    acc += __shfl_xor(acc, 2);
    acc += __shfl_xor(acc, 4);
    acc += __shfl_xor(acc, 8);
    if (l16 == 0) gates_lds[r] = acc;
    __syncthreads();

    // cell update: 8 h-dims, one per thread 0..7
    if (tid < 8) {
      float gi = gates_lds[tid]      + xv0;
      float gf = gates_lds[8 + tid]  + xv1;
      float gg = gates_lds[16 + tid] + xv2;
      float go = gates_lds[24 + tid] + xv3;
      float si = 1.f / (1.f + __expf(-gi));
      float sf = 1.f / (1.f + __expf(-gf));
      float so = 1.f / (1.f + __expf(-go));
      float tg = 1.f - 2.f / (1.f + __expf(2.f * gg));
      c = sf * c + si * tg;
      float th = 1.f - 2.f / (1.f + __expf(2.f * c));
      float h  = so * th;
      histd[(size_t)tau * 1024 + wsl * 8 + tid] = h;
      unsigned long long pk = ((unsigned long long)(unsigned)t << 32)
                            | (unsigned long long)__float_as_uint(h);
      __hip_atomic_store(&g_ring[dir][t & 1][wsl * 8 + tid], pk,
                         __ATOMIC_RELAXED, __HIP_MEMORY_SCOPE_AGENT);
    }
    // no trailing barrier: h_lds rewrites in t+1 are fenced by the post-poll
    // barrier; gates_lds rewrites by the post-GEMV barrier.
  }
}

// ---------------- feats = concat(h_f,h_b) @ W_lin^T + b_lin ----------------
__global__ __launch_bounds__(256, 1) void feats_kernel(
    const float* __restrict__ W_lin, const float* __restrict__ b_lin)
{
  const int tid = threadIdx.x;
  const int wv = tid >> 6, l = tid & 63;
  const int t0 = blockIdx.x * 16 + wv * 4;
  for (int it = 0; it < 4; ++it) {
    const int t = t0 + it;
    float hf[16], hbv[16];
#pragma unroll
    for (int i = 0; i < 16; ++i) hf[i]  = g_hist[(size_t)t * 1024 + l + 64 * i];
#pragma unroll
    for (int i = 0; i < 16; ++i) hbv[i] = g_hist[(size_t)(4096 + t) * 1024 + l + 64 * i];
#pragma unroll
    for (int tag = 0; tag < 10; ++tag) {
      float a = 0.f;
#pragma unroll
      for (int i = 0; i < 16; ++i) {
        a += W_lin[tag * 2048 + l + 64 * i] * hf[i];
        a += W_lin[tag * 2048 + 1024 + l + 64 * i] * hbv[i];
      }
      a += __shfl_xor(a, 32); a += __shfl_xor(a, 16); a += __shfl_xor(a, 8);
      a += __shfl_xor(a, 4);  a += __shfl_xor(a, 2);  a += __shfl_xor(a, 1);
      if (l == 0) g_feats[t * 10 + tag] = a + b_lin[tag];
    }
  }
}

// ---------------- Viterbi forward + backtrack ----------------
__global__ __launch_bounds__(64, 1) void viterbi_kernel(
    const float* __restrict__ trans, float* __restrict__ out)
{
  __shared__ unsigned char bps[4096 * 10];
  const int to = threadIdx.x;
  float tr[10];
#pragma unroll
  for (int f = 0; f < 10; ++f) tr[f] = (to < 10) ? trans[to * 10 + f] : 0.f;
  float fv = (to == 8) ? 0.f : -10000.f;   // START_TAG = 8

  float fbuf[8];
#pragma unroll
  for (int i = 0; i < 8; ++i) fbuf[i] = (to < 10) ? g_feats[i * 10 + to] : 0.f;

  for (int t = 0; t < 4096; t += 8) {
#pragma unroll
    for (int u = 0; u < 8; ++u) {
      const int tt = t + u;
      float m = -3.4e38f; int am = 0;
#pragma unroll
      for (int f = 0; f < 10; ++f) {
        float v = __shfl(fv, f) + tr[f];
        if (v > m) { m = v; am = f; }
      }
      float ft = fbuf[u];
      if (tt + 8 < 4096 && to < 10) fbuf[u] = g_feats[(tt + 8) * 10 + to];
      fv = m + ft;
      if (to < 10) bps[tt * 10 + to] = (unsigned char)am;
    }
  }
  __syncthreads();

  float term = fv + ((to < 10) ? trans[90 + to] : -3.4e38f);  // STOP_TAG row
  float best = -3.4e38f; int bl = 0;
#pragma unroll
  for (int f = 0; f < 10; ++f) {
    float v = __shfl(term, f);
    if (v > best) { best = v; bl = f; }
  }
  if (to == 0) {
    out[0] = best;
    int tag = bl;
    for (int t = 4095; t >= 0; --t) {
      out[1 + t] = (float)tag;
      tag = bps[t * 10 + tag];
    }
  }
}

// ---------------- launch ----------------
extern "C" void kernel_launch(void* const* d_in, const int* in_sizes, int n_in,
                              void* d_out, int out_size, void* d_ws, size_t ws_size,
                              hipStream_t stream)
{
  (void)in_sizes; (void)n_in; (void)out_size; (void)d_ws; (void)ws_size;
  const float* W_hh_f   = (const float*)d_in[2];
  const float* b_f      = (const float*)d_in[3];
  const float* W_hh_b   = (const float*)d_in[5];
  const float* b_b      = (const float*)d_in[6];
  const float* W_lin    = (const float*)d_in[7];
  const float* b_lin    = (const float*)d_in[8];
  const float* trans    = (const float*)d_in[9];

  cvt_split<<<1024, 256, 0, stream>>>((const float*)d_in[0], 0, 2097152);
  cvt_split<<<1024, 256, 0, stream>>>((const float*)d_in[1], 1, 2097152);
  cvt_split<<<1024, 256, 0, stream>>>((const float*)d_in[4], 2, 2097152);

  gemm_xp<<<dim3(32, 32, 2), 256, 0, stream>>>(b_f, b_b);

  init_sync<<<16, 256, 0, stream>>>();

  lstm_persistent<<<256, 512, 0, stream>>>(W_hh_f, W_hh_b);

  feats_kernel<<<256, 256, 0, stream>>>(W_lin, b_lin);

  viterbi_kernel<<<1, 64, 0, stream>>>(trans, (float*)d_out);
}

// Round 5
// 11512.848 us; speedup vs baseline: 3.6745x; 1.1521x over previous
//
#include <hip/hip_runtime.h>

typedef _Float16 f16;
typedef _Float16 f16x4 __attribute__((ext_vector_type(4)));
typedef _Float16 f16x8 __attribute__((ext_vector_type(8)));
typedef float f32x4 __attribute__((ext_vector_type(4)));
typedef unsigned u32x4 __attribute__((ext_vector_type(4)));

#define SEQ 4096
#define NF  2048
#define HID 1024

// ---------------- static device scratch ----------------
__device__ f16   g_Ahi[SEQ * NF];
__device__ f16   g_Alo[SEQ * NF];
__device__ f16   g_Whi[2 * 4096 * NF];
__device__ f16   g_Wlo[2 * 4096 * NF];
__device__ float g_xp [2u * SEQ * 4096u];          // [dir][t][4096]
__device__ float g_hist[2u * SEQ * HID];           // [dir][t][1024]
__device__ unsigned long long g_ring[2][2][1024];  // [dir][slot][j] = tag<<32 | h_bits
__device__ float g_feats[SEQ * 10];

// ---------------- fp32 -> f16 hi/lo split ----------------
__global__ void cvt_split(const float* __restrict__ src, int which, int n4) {
  int i = blockIdx.x * blockDim.x + threadIdx.x;
  int stride = gridDim.x * blockDim.x;
  f16* hi; f16* lo;
  if (which == 0)      { hi = g_Ahi; lo = g_Alo; }
  else if (which == 1) { hi = g_Whi; lo = g_Wlo; }
  else                 { hi = g_Whi + 4096 * NF; lo = g_Wlo + 4096 * NF; }
  const float4* s4 = (const float4*)src;
  f16x4* h4 = (f16x4*)hi;
  f16x4* l4 = (f16x4*)lo;
  for (int idx = i; idx < n4; idx += stride) {
    float4 v = s4[idx];
    f16x4 h, l;
    h.x = (f16)v.x; l.x = (f16)(v.x - (float)h.x);
    h.y = (f16)v.y; l.y = (f16)(v.y - (float)h.y);
    h.z = (f16)v.z; l.z = (f16)(v.z - (float)h.z);
    h.w = (f16)v.w; l.w = (f16)(v.w - (float)h.w);
    h4[idx] = h; l4[idx] = l;
  }
}

// ---------------- xp = A @ W^T + b  (split f16, 3 MFMA products) ----------------
__global__ __launch_bounds__(256, 1) void gemm_xp(
    const float* __restrict__ b_f, const float* __restrict__ b_b)
{
  const int d = blockIdx.z;
  const f16* WhiD = g_Whi + (size_t)d * (4096u * 2048u);
  const f16* WloD = g_Wlo + (size_t)d * (4096u * 2048u);
  const float* bias = d ? b_b : b_f;
  float* out = g_xp + (size_t)d * (4096u * 4096u);

  __shared__ f16 sAh[128 * 40];
  __shared__ f16 sAl[128 * 40];
  __shared__ f16 sWh[128 * 40];
  __shared__ f16 sWl[128 * 40];

  const int tid  = threadIdx.x;
  const int lane = tid & 63;
  const int wv   = tid >> 6;
  const int quad = lane >> 4;
  const int mrow = lane & 15;
  const int m0 = (wv & 1) * 64;
  const int n0 = (wv >> 1) * 64;
  const int bm = blockIdx.y, bn = blockIdx.x;

  f32x4 acc[4][4] = {};

  const int r0  = tid >> 2;
  const int seg = tid & 3;

  for (int kt = 0; kt < 2048; kt += 32) {
#pragma unroll
    for (int r = 0; r < 2; ++r) {
      int row = r * 64 + r0;
      size_t ga = (size_t)(bm * 128 + row) * 2048 + kt + seg * 8;
      size_t gw = (size_t)(bn * 128 + row) * 2048 + kt + seg * 8;
      int lidx = row * 40 + seg * 8;
      *(f16x8*)&sAh[lidx] = *(const f16x8*)&g_Ahi[ga];
      *(f16x8*)&sAl[lidx] = *(const f16x8*)&g_Alo[ga];
      *(f16x8*)&sWh[lidx] = *(const f16x8*)&WhiD[gw];
      *(f16x8*)&sWl[lidx] = *(const f16x8*)&WloD[gw];
    }
    __syncthreads();

    f16x8 ah[4], al[4], wh[4], wl[4];
#pragma unroll
    for (int mi = 0; mi < 4; ++mi) {
      int rowm = (m0 + mi * 16 + mrow) * 40 + quad * 8;
      ah[mi] = *(const f16x8*)&sAh[rowm];
      al[mi] = *(const f16x8*)&sAl[rowm];
    }
#pragma unroll
    for (int ni = 0; ni < 4; ++ni) {
      int rown = (n0 + ni * 16 + mrow) * 40 + quad * 8;
      wh[ni] = *(const f16x8*)&sWh[rown];
      wl[ni] = *(const f16x8*)&sWl[rown];
    }
#pragma unroll
    for (int mi = 0; mi < 4; ++mi)
#pragma unroll
      for (int ni = 0; ni < 4; ++ni) {
        acc[mi][ni] = __builtin_amdgcn_mfma_f32_16x16x32_f16(ah[mi], wh[ni], acc[mi][ni], 0, 0, 0);
        acc[mi][ni] = __builtin_amdgcn_mfma_f32_16x16x32_f16(ah[mi], wl[ni], acc[mi][ni], 0, 0, 0);
        acc[mi][ni] = __builtin_amdgcn_mfma_f32_16x16x32_f16(al[mi], wh[ni], acc[mi][ni], 0, 0, 0);
      }
    __syncthreads();
  }

#pragma unroll
  for (int ni = 0; ni < 4; ++ni) {
    int g = bn * 128 + n0 + ni * 16 + mrow;
    float bv = bias[g];
#pragma unroll
    for (int mi = 0; mi < 4; ++mi) {
#pragma unroll
      for (int r = 0; r < 4; ++r) {
        int t = bm * 128 + m0 + mi * 16 + quad * 4 + r;
        out[(size_t)t * 4096 + g] = acc[mi][ni][r] + bv;
      }
    }
  }
}

// ---------------- per-call ring reset (graph-replay safe) ----------------
__global__ void init_sync() {
  int i = blockIdx.x * blockDim.x + threadIdx.x;
  ((unsigned long long*)g_ring)[i] = 0ull;   // tag 0, h = 0.0f
}

// ---------------- persistent bidirectional LSTM ----------------
// 128 WGs x 1024 threads. dir = bid&1, wsl = bid>>1 (16 h-dims per WG).
// 64 rows/WG (4 gates x 16 dims), 16 lanes per row; thread covers
// k in {4*l16 + 64*j : j=0..15} -> 64 FMA/thread/step.
// Sync: h element = one u64 (tag<<32 | fp32 bits) in a 2-slot ring.
// Producer: 8B atomic sc0/sc1 stores (16/WG). Consumer: WIDE NON-ATOMIC
// coherent loads (global_load_dwordx4 sc0 sc1, 2 elems per transaction,
// 512 loaders/WG) — this cuts MALL transactions ~4x vs R4's per-8B
// atomic polling (262K -> 65K per step), which the R4 counters implicate
// as the serial bottleneck (VALU work rose 38% with no dur change ->
// chain is in the memory/sync path, not compute).
__global__ __launch_bounds__(1024) void lstm_persistent(
    const float* __restrict__ Whh_f, const float* __restrict__ Whh_b)
{
  const int bid = blockIdx.x;
  const int dir = bid & 1;
  const int wsl = bid >> 1;        // 0..63
  const int tid = threadIdx.x;
  const int r   = tid >> 4;        // local row 0..63 (gate = r>>4, jj = r&15)
  const int l16 = tid & 15;

  __shared__ float h_lds[1024];
  __shared__ float gates_lds[64];

  const float* Wd = dir ? Whh_b : Whh_f;

  // one-time weight load: row grow, cols 4*l16 + 64*j
  const int grow = (r >> 4) * 1024 + wsl * 16 + (r & 15);
  float4 w4[16];
#pragma unroll
  for (int j = 0; j < 16; ++j)
    w4[j] = *(const float4*)&Wd[(size_t)grow * 1024 + 4 * l16 + 64 * j];

  const float* xpd = g_xp + (size_t)dir * 4096u * 4096u;
  float* histd = g_hist + (size_t)dir * 4096u * 1024u;

  float c = 0.f;

  for (int t = 1; t <= 4096; ++t) {
    const int tau = dir ? (4096 - t) : (t - 1);

    // prefetch xp contribution (consumed in the update stage)
    float xv0 = 0.f, xv1 = 0.f, xv2 = 0.f, xv3 = 0.f;
    if (tid < 16) {
      const float* px = xpd + (size_t)tau * 4096 + wsl * 16 + tid;
      xv0 = px[0]; xv1 = px[1024]; xv2 = px[2048]; xv3 = px[3072];
    }

    // poll ring for h_{t-1}: 512 loader threads, 2 elems (16B) each,
    // via wide coherent non-atomic load (L1/L2-bypassing sc0 sc1).
    if (tid < 512) {
      const unsigned need = (unsigned)(t - 1);
      const unsigned long long* rs = &g_ring[dir][(t - 1) & 1][0] + 2 * tid;
      u32x4 q;
      for (;;) {
        asm volatile("global_load_dwordx4 %0, %1, off sc0 sc1\n\t"
                     "s_waitcnt vmcnt(0)"
                     : "=v"(q) : "v"(rs) : "memory");
        // little-endian: q.x = bits0, q.y = tag0, q.z = bits1, q.w = tag1
        if (q.y == need && q.w == need) break;
        __builtin_amdgcn_s_sleep(1);
      }
      float2 hv;
      hv.x = __uint_as_float(q.x);
      hv.y = __uint_as_float(q.z);
      *(float2*)&h_lds[2 * tid] = hv;
    }
    __syncthreads();

    // GEMV: 1 row x 64 k per thread, 4-way ILP partials
    float p0 = 0.f, p1 = 0.f, p2 = 0.f, p3 = 0.f;
#pragma unroll
    for (int j = 0; j < 16; j += 4) {
      float4 h0 = *(const float4*)&h_lds[4 * l16 + 64 * (j + 0)];
      float4 h1 = *(const float4*)&h_lds[4 * l16 + 64 * (j + 1)];
      float4 h2 = *(const float4*)&h_lds[4 * l16 + 64 * (j + 2)];
      float4 h3 = *(const float4*)&h_lds[4 * l16 + 64 * (j + 3)];
      p0 += w4[j+0].x*h0.x + w4[j+0].y*h0.y + w4[j+0].z*h0.z + w4[j+0].w*h0.w;
      p1 += w4[j+1].x*h1.x + w4[j+1].y*h1.y + w4[j+1].z*h1.z + w4[j+1].w*h1.w;
      p2 += w4[j+2].x*h2.x + w4[j+2].y*h2.y + w4[j+2].z*h2.z + w4[j+2].w*h2.w;
      p3 += w4[j+3].x*h3.x + w4[j+3].y*h3.y + w4[j+3].z*h3.z + w4[j+3].w*h3.w;
    }
    float acc = (p0 + p1) + (p2 + p3);
    acc += __shfl_xor(acc, 1);
    acc += __shfl_xor(acc, 2);
    acc += __shfl_xor(acc, 4);
    acc += __shfl_xor(acc, 8);
    if (l16 == 0) gates_lds[r] = acc;
    __syncthreads();

    // cell update: 16 h-dims, one per thread 0..15
    if (tid < 16) {
      float gi = gates_lds[tid]      + xv0;
      float gf = gates_lds[16 + tid] + xv1;
      float gg = gates_lds[32 + tid] + xv2;
      float go = gates_lds[48 + tid] + xv3;
      float si = 1.f / (1.f + __expf(-gi));
      float sf = 1.f / (1.f + __expf(-gf));
      float so = 1.f / (1.f + __expf(-go));
      float tg = 1.f - 2.f / (1.f + __expf(2.f * gg));
      c = sf * c + si * tg;
      float th = 1.f - 2.f / (1.f + __expf(2.f * c));
      float h  = so * th;
      histd[(size_t)tau * 1024 + wsl * 16 + tid] = h;
      unsigned long long pk = ((unsigned long long)(unsigned)t << 32)
                            | (unsigned long long)__float_as_uint(h);
      __hip_atomic_store(&g_ring[dir][t & 1][wsl * 16 + tid], pk,
                         __ATOMIC_RELAXED, __HIP_MEMORY_SCOPE_AGENT);
    }
    // no trailing barrier: h_lds rewrites in t+1 are fenced by the post-poll
    // barrier; gates_lds rewrites by the post-GEMV barrier.
  }
}

// ---------------- feats = concat(h_f,h_b) @ W_lin^T + b_lin ----------------
__global__ __launch_bounds__(256, 1) void feats_kernel(
    const float* __restrict__ W_lin, const float* __restrict__ b_lin)
{
  const int tid = threadIdx.x;
  const int wv = tid >> 6, l = tid & 63;
  const int t0 = blockIdx.x * 16 + wv * 4;
  for (int it = 0; it < 4; ++it) {
    const int t = t0 + it;
    float hf[16], hbv[16];
#pragma unroll
    for (int i = 0; i < 16; ++i) hf[i]  = g_hist[(size_t)t * 1024 + l + 64 * i];
#pragma unroll
    for (int i = 0; i < 16; ++i) hbv[i] = g_hist[(size_t)(4096 + t) * 1024 + l + 64 * i];
#pragma unroll
    for (int tag = 0; tag < 10; ++tag) {
      float a = 0.f;
#pragma unroll
      for (int i = 0; i < 16; ++i) {
        a += W_lin[tag * 2048 + l + 64 * i] * hf[i];
        a += W_lin[tag * 2048 + 1024 + l + 64 * i] * hbv[i];
      }
      a += __shfl_xor(a, 32); a += __shfl_xor(a, 16); a += __shfl_xor(a, 8);
      a += __shfl_xor(a, 4);  a += __shfl_xor(a, 2);  a += __shfl_xor(a, 1);
      if (l == 0) g_feats[t * 10 + tag] = a + b_lin[tag];
    }
  }
}

// ---------------- Viterbi forward + backtrack ----------------
__global__ __launch_bounds__(64, 1) void viterbi_kernel(
    const float* __restrict__ trans, float* __restrict__ out)
{
  __shared__ unsigned char bps[4096 * 10];
  const int to = threadIdx.x;
  float tr[10];
#pragma unroll
  for (int f = 0; f < 10; ++f) tr[f] = (to < 10) ? trans[to * 10 + f] : 0.f;
  float fv = (to == 8) ? 0.f : -10000.f;   // START_TAG = 8

  float fbuf[8];
#pragma unroll
  for (int i = 0; i < 8; ++i) fbuf[i] = (to < 10) ? g_feats[i * 10 + to] : 0.f;

  for (int t = 0; t < 4096; t += 8) {
#pragma unroll
    for (int u = 0; u < 8; ++u) {
      const int tt = t + u;
      float m = -3.4e38f; int am = 0;
#pragma unroll
      for (int f = 0; f < 10; ++f) {
        float v = __shfl(fv, f) + tr[f];
        if (v > m) { m = v; am = f; }
      }
      float ft = fbuf[u];
      if (tt + 8 < 4096 && to < 10) fbuf[u] = g_feats[(tt + 8) * 10 + to];
      fv = m + ft;
      if (to < 10) bps[tt * 10 + to] = (unsigned char)am;
    }
  }
  __syncthreads();

  float term = fv + ((to < 10) ? trans[90 + to] : -3.4e38f);  // STOP_TAG row
  float best = -3.4e38f; int bl = 0;
#pragma unroll
  for (int f = 0; f < 10; ++f) {
    float v = __shfl(term, f);
    if (v > best) { best = v; bl = f; }
  }
  if (to == 0) {
    out[0] = best;
    int tag = bl;
    for (int t = 4095; t >= 0; --t) {
      out[1 + t] = (float)tag;
      tag = bps[t * 10 + tag];
    }
  }
}

// ---------------- launch ----------------
extern "C" void kernel_launch(void* const* d_in, const int* in_sizes, int n_in,
                              void* d_out, int out_size, void* d_ws, size_t ws_size,
                              hipStream_t stream)
{
  (void)in_sizes; (void)n_in; (void)out_size; (void)d_ws; (void)ws_size;
  const float* W_hh_f   = (const float*)d_in[2];
  const float* b_f      = (const float*)d_in[3];
  const float* W_hh_b   = (const float*)d_in[5];
  const float* b_b      = (const float*)d_in[6];
  const float* W_lin    = (const float*)d_in[7];
  const float* b_lin    = (const float*)d_in[8];
  const float* trans    = (const float*)d_in[9];

  cvt_split<<<1024, 256, 0, stream>>>((const float*)d_in[0], 0, 2097152);
  cvt_split<<<1024, 256, 0, stream>>>((const float*)d_in[1], 1, 2097152);
  cvt_split<<<1024, 256, 0, stream>>>((const float*)d_in[4], 2, 2097152);

  gemm_xp<<<dim3(32, 32, 2), 256, 0, stream>>>(b_f, b_b);

  init_sync<<<16, 256, 0, stream>>>();

  lstm_persistent<<<128, 1024, 0, stream>>>(W_hh_f, W_hh_b);

  feats_kernel<<<256, 256, 0, stream>>>(W_lin, b_lin);

  viterbi_kernel<<<1, 64, 0, stream>>>(trans, (float*)d_out);
}